// Round 13
// baseline (313.658 us; speedup 1.0000x reference)
//
#include <hip/hip_runtime.h>
#include <hip/hip_fp16.h>
#include <math.h>

#define N_NODES 100000
#define N_EDGES 3200000
#define N_GRAPHS 64
#define NEG_INF -1e30f

// bucket sort geometry: bucket = dst >> 9  (512 nodes per bucket)
#define NB 196         // ceil(100000/512)
#define CAP 18432      // per-bucket capacity; mean 16384 + ~16 sigma
#define NBLK 512       // partition blocks
#define CHUNK 6250     // 512 * 6250 = 3.2M exactly

__device__ __forceinline__ void atomAddF(float* p, float v) {
#if defined(__HIP_PLATFORM_AMD__)
    unsafeAtomicAdd(p, v);
#else
    atomicAdd(p, v);
#endif
}

__device__ __forceinline__ float b2f(unsigned w, int sh) {
    return (float)(signed char)(w >> sh);
}

// logit from packed kv row; also extracts v-scale
__device__ __forceinline__ float kvdot(const float* q, uint4 w, float* sv_out) {
    float2 s = __half22float2(*(const __half2*)&w.w);
    *sv_out = s.y;
    return s.x * (q[0] * b2f(w.x, 0) + q[1] * b2f(w.x, 8)
                + q[2] * b2f(w.x, 16) + q[3] * b2f(w.x, 24)
                + q[4] * b2f(w.y, 0) + q[5] * b2f(w.y, 8));
}

// ---- S1: (merged) x-pack + zero-init + in-LDS bucket sort of chunk ----
__global__ __launch_bounds__(512) void s1_partition(const int* __restrict__ ei,
                                                    const float* __restrict__ x,
                                                    float4* __restrict__ xp,
                                                    uint2* __restrict__ xh,
                                                    float* __restrict__ psum,
                                                    float* __restrict__ pcnt,
                                                    int* __restrict__ done,
                                                    int* __restrict__ offs,
                                                    unsigned* __restrict__ pairs) {
    __shared__ unsigned pairbuf[CHUNK];        // 25000 B
    __shared__ unsigned sortbuf[CHUNK];        // 25000 B
    __shared__ unsigned char buckbuf[CHUNK];   // 6250 B
    __shared__ int hist[8][200];               // per-wave, padded
    __shared__ int cur[NB], tmp[NB];
    int tid = threadIdx.x;

    // merged k0: pack this block's slice of nodes (196 per block covers 100352)
    {
        int n = blockIdx.x * 196 + tid;
        if (tid < 196 && n < N_NODES) {
            float x0 = x[3 * n], x1 = x[3 * n + 1], x2 = x[3 * n + 2];
            xp[n] = make_float4(x0, x1, x2, 0.f);
            __half2 h01 = __floats2half2_rn(x0, x1);
            __half2 h2p = __floats2half2_rn(x2, 0.f);
            xh[n] = make_uint2(*(unsigned*)&h01, *(unsigned*)&h2p);
        }
    }
    // merged zero-init (block 0): psum, pcnt, done
    if (blockIdx.x == 0) {
        for (int i = tid; i < N_GRAPHS * 6; i += 512) psum[i] = 0.f;
        for (int i = tid; i < N_GRAPHS; i += 512) pcnt[i] = 0.f;
        if (tid == 0) *done = 0;
    }

    int wp = tid >> 6;                         // 8 waves
    for (int i = tid; i < 8 * 200; i += 512) ((int*)hist)[i] = 0;
    __syncthreads();
    int gbase = blockIdx.x * CHUNK;
    for (int i = tid; i < CHUNK; i += 512) {
        int src = ei[gbase + i];
        unsigned dst = (unsigned)ei[N_EDGES + gbase + i];
        pairbuf[i] = ((unsigned)src << 9) | (dst & 511u);
        unsigned b = dst >> 9;
        buckbuf[i] = (unsigned char)b;
        atomicAdd(&hist[wp][b], 1);
    }
    __syncthreads();
    if (tid < NB) {
        int s = 0;
#pragma unroll
        for (int w = 0; w < 8; ++w) s += hist[w][tid];
        tmp[tid] = s;
        hist[0][tid] = s;                      // stash count for later
    }
    __syncthreads();
    for (int off = 1; off < NB; off <<= 1) {
        int v = 0;
        if (tid < NB && tid >= off) v = tmp[tid - off];
        __syncthreads();
        if (tid < NB) tmp[tid] += v;
        __syncthreads();
    }
    if (tid < NB) {
        int excl = tmp[tid] - hist[0][tid];
        cur[tid] = excl;
        offs[blockIdx.x * NB + tid] = excl;
    }
    __syncthreads();
    for (int i = tid; i < CHUNK; i += 512) {
        int pos = atomicAdd(&cur[buckbuf[i]], 1);
        sortbuf[pos] = pairbuf[i];
    }
    __syncthreads();
    for (int i = tid; i < CHUNK; i += 512)
        pairs[gbase + i] = sortbuf[i];
}

// ---- B4: per-bucket CSR build with full-bucket LDS staging ----
#define B4T 1024
__global__ __launch_bounds__(B4T) void b4_build(const unsigned* __restrict__ pairs,
                                                const int* __restrict__ offs,
                                                int* __restrict__ rs,
                                                int* __restrict__ re,
                                                int* __restrict__ csr_src) {
    __shared__ unsigned eLDS[CAP];             // 73728 B: bucket's edges, dense
    __shared__ int so[NBLK], slen[NBLK], dbase[NBLK];
    __shared__ int cnt2[2][512];
    __shared__ int sc[512], cur[512];
    int b = blockIdx.x;
    int tid = threadIdx.x;

    for (int k = tid; k < NBLK; k += B4T) {
        int s = offs[k * NB + b];
        int e = (b == NB - 1) ? CHUNK : offs[k * NB + b + 1];
        so[k] = s;
        slen[k] = e - s;
    }
    ((int*)cnt2)[tid] = 0;
    __syncthreads();
    // inclusive scan of slen -> dbase (exclusive via -slen)
    if (tid < NBLK) sc[tid] = slen[tid];
    __syncthreads();
    for (int off = 1; off < NBLK; off <<= 1) {
        int v = (tid < NBLK && tid >= off) ? sc[tid - off] : 0;
        __syncthreads();
        if (tid < NBLK) sc[tid] += v;
        __syncthreads();
    }
    if (tid < NBLK) dbase[tid] = sc[tid] - slen[tid];
    __syncthreads();
    int ne = dbase[NBLK - 1] + slen[NBLK - 1];

    // coalesced copy: wave per segment
    int wave = tid >> 6, lane = tid & 63;
    for (int k = wave; k < NBLK; k += (B4T / 64)) {
        int gb = k * CHUNK + so[k];
        int db = dbase[k], ln = slen[k];
        for (int i = lane; i < ln; i += 64)
            eLDS[db + i] = pairs[gb + i];
    }
    __syncthreads();

    // count (from LDS), dual sub-histograms to cut conflicts
    int half = tid >> 9;
    for (int i = tid; i < ne; i += B4T)
        atomicAdd(&cnt2[half][eLDS[i] & 511u], 1);
    __syncthreads();
    int mycnt = 0;
    if (tid < 512) {
        mycnt = cnt2[0][tid] + cnt2[1][tid];
        sc[tid] = mycnt;
    }
    __syncthreads();
    for (int off = 1; off < 512; off <<= 1) {
        int v = (tid < 512 && tid >= off) ? sc[tid - off] : 0;
        __syncthreads();
        if (tid < 512) sc[tid] += v;
        __syncthreads();
    }
    int rbase = b * CAP;
    if (tid < 512) {
        int excl = sc[tid] - mycnt;
        cur[tid] = rbase + excl;
        int node = (b << 9) + tid;
        if (node < N_NODES) {
            rs[node] = rbase + excl;
            re[node] = rbase + sc[tid];
        }
    }
    __syncthreads();
    // scatter (read LDS, write bucket-local global slice)
    for (int i = tid; i < ne; i += B4T) {
        unsigned p = eLDS[i];
        int pos = atomicAdd(&cur[p & 511u], 1);
        csr_src[pos] = (int)(p >> 9);
    }
}

// ---- G1: fused layer-1, rank-3 factorization, fp16 x-gathers, fp16 h1 out ----
__global__ void g1_layer1(const float4* __restrict__ xp,
                          const uint2* __restrict__ xh,
                          const float* __restrict__ Wq, const float* __restrict__ bq,
                          const float* __restrict__ Wk, const float* __restrict__ bk,
                          const float* __restrict__ Wv, const float* __restrict__ bv,
                          const float* __restrict__ Ws, const float* __restrict__ bs,
                          const int* __restrict__ rs, const int* __restrict__ re,
                          const int* __restrict__ csr_src,
                          uint2* __restrict__ h1) {
    __shared__ float sWq[192], sWk[192], sWv[192], sWs[192];
    __shared__ float sbq[64], sbk[64], sbv[64], sbs[64];
    for (int i = threadIdx.x; i < 192; i += 256) {
        sWq[i] = Wq[i]; sWk[i] = Wk[i]; sWv[i] = Wv[i]; sWs[i] = Ws[i];
    }
    for (int i = threadIdx.x; i < 64; i += 256) {
        sbq[i] = bq[i]; sbk[i] = bk[i]; sbv[i] = bv[i]; sbs[i] = bs[i];
    }
    __syncthreads();

    int lane = threadIdx.x & 63;
    int u = lane & 15;
    int slot = u >> 2;
    int j0 = u * 4;
    int n = blockIdx.x * 16 + (threadIdx.x >> 6) * 4 + (lane >> 4);

    float4 xc = xp[n];
    float x0 = xc.x, x1 = xc.y, x2 = xc.z;

    float q[4];
#pragma unroll
    for (int i = 0; i < 4; ++i)
        q[i] = 0.25f * (sbq[j0 + i] + x0 * sWq[j0 + i] + x1 * sWq[64 + j0 + i]
                        + x2 * sWq[128 + j0 + i]);
    float t0 = 0.f, t1 = 0.f, t2 = 0.f, tb = 0.f;
#pragma unroll
    for (int i = 0; i < 4; ++i) {
        float qi = q[i];
        t0 += qi * sWk[j0 + i];
        t1 += qi * sWk[64 + j0 + i];
        t2 += qi * sWk[128 + j0 + i];
        tb += qi * sbk[j0 + i];
    }
#pragma unroll
    for (int off = 1; off <= 2; off <<= 1) {
        t0 += __shfl_xor(t0, off);
        t1 += __shfl_xor(t1, off);
        t2 += __shfl_xor(t2, off);
        tb += __shfl_xor(tb, off);
    }
    // transpose: edge loop wants head = u&3
    int tsrc = (lane & 48) | ((lane & 3) << 2) | ((lane >> 2) & 3);
    t0 = __shfl(t0, tsrc, 64);
    t1 = __shfl(t1, tsrc, 64);
    t2 = __shfl(t2, tsrc, 64);
    tb = __shfl(tb, tsrc, 64);

    int row = rs[n];
    int deg = re[n] - row;

    float mA = NEG_INF, dA = 0.f, s0A = 0.f, s1A = 0.f, s2A = 0.f;
    float mB = NEG_INF, dB = 0.f, s0B = 0.f, s1B = 0.f, s2B = 0.f;
    for (int base = 0; base < deg; base += 8) {
        int eA = base + slot, eB = base + 4 + slot;
        bool vA = eA < deg, vB = eB < deg;
        int srcA = vA ? csr_src[row + eA] : 0;
        int srcB = vB ? csr_src[row + eB] : 0;
        uint2 wA = xh[srcA];
        uint2 wB = xh[srcB];
        float2 a01 = __half22float2(*(const __half2*)&wA.x);
        float a2 = __half22float2(*(const __half2*)&wA.y).x;
        float2 b01 = __half22float2(*(const __half2*)&wB.x);
        float b2 = __half22float2(*(const __half2*)&wB.y).x;
        float lA = vA ? (tb + a01.x * t0 + a01.y * t1 + a2 * t2) : NEG_INF;
        float lB = vB ? (tb + b01.x * t0 + b01.y * t1 + b2 * t2) : NEG_INF;
        float mnA = fmaxf(mA, lA);
        float scA = __expf(mA - mnA);
        float aA = vA ? __expf(lA - mnA) : 0.f;
        dA = dA * scA + aA;
        s0A = s0A * scA + aA * a01.x;
        s1A = s1A * scA + aA * a01.y;
        s2A = s2A * scA + aA * a2;
        mA = mnA;
        float mnB = fmaxf(mB, lB);
        float scB = __expf(mB - mnB);
        float aB = vB ? __expf(lB - mnB) : 0.f;
        dB = dB * scB + aB;
        s0B = s0B * scB + aB * b01.x;
        s1B = s1B * scB + aB * b01.y;
        s2B = s2B * scB + aB * b2;
        mB = mnB;
    }
    // merge B into A (in-lane)
    float m = fmaxf(mA, mB);
    float fA = __expf(mA - m), fB = __expf(mB - m);
    float d = dA * fA + dB * fB;
    float s0 = s0A * fA + s0B * fB;
    float s1 = s1A * fA + s1B * fB;
    float s2 = s2A * fA + s2B * fB;

    // cross-slot merge: global max, single rescale, butterfly sums
    float gm = m;
    gm = fmaxf(gm, __shfl_xor(gm, 4));
    gm = fmaxf(gm, __shfl_xor(gm, 8));
    float f = __expf(m - gm);
    d *= f; s0 *= f; s1 *= f; s2 *= f;
#pragma unroll
    for (int off = 4; off <= 8; off <<= 1) {
        d += __shfl_xor(d, off);
        s0 += __shfl_xor(s0, off);
        s1 += __shfl_xor(s1, off);
        s2 += __shfl_xor(s2, off);
    }

    // epilogue: lane u needs head u>>2's state
    int esrc = (lane & 48) | ((lane >> 2) & 3);
    float dH = __shfl(d, esrc, 64);
    float s0H = __shfl(s0, esrc, 64);
    float s1H = __shfl(s1, esrc, 64);
    float s2H = __shfl(s2, esrc, 64);
    float inv = 1.f / (dH + 1e-16f);
    float fr = dH * inv, r0 = s0H * inv, r1 = s1H * inv, r2 = s2H * inv;

    float o[4];
#pragma unroll
    for (int i = 0; i < 4; ++i) {
        int j = j0 + i;
        float val = fr * sbv[j] + r0 * sWv[j] + r1 * sWv[64 + j] + r2 * sWv[128 + j]
                  + sbs[j] + x0 * sWs[j] + x1 * sWs[64 + j] + x2 * sWs[128 + j];
        o[i] = fmaxf(val, 0.f);
    }
    __half2 p01 = __floats2half2_rn(o[0], o[1]);
    __half2 p23 = __floats2half2_rn(o[2], o[3]);
    h1[(size_t)n * 16 + u] = make_uint2(*(unsigned*)&p01, *(unsigned*)&p23);
}

// ---- K5: reads fp16 h1; q2h fp16-packed (pre-scaled) + s2 fp32; kv2 int8 ----
__global__ void k5_node2(const unsigned* __restrict__ h1,
                         const float* __restrict__ Wq, const float* __restrict__ bq,
                         const float* __restrict__ Wk, const float* __restrict__ bk,
                         const float* __restrict__ Wv, const float* __restrict__ bv,
                         const float* __restrict__ Ws, const float* __restrict__ bs,
                         uint4* __restrict__ q2h, float* __restrict__ s2,
                         uint4* __restrict__ kv2) {
    __shared__ float sWq[384], sWk[384], sWv[384], sWs[384];
    __shared__ float sbq[6], sbk[6], sbv[6], sbs[6];
    for (int i = threadIdx.x; i < 384; i += blockDim.x) {
        sWq[i] = Wq[i]; sWk[i] = Wk[i]; sWv[i] = Wv[i]; sWs[i] = Ws[i];
    }
    if (threadIdx.x < 6) {
        sbq[threadIdx.x] = bq[threadIdx.x];
        sbk[threadIdx.x] = bk[threadIdx.x];
        sbv[threadIdx.x] = bv[threadIdx.x];
        sbs[threadIdx.x] = bs[threadIdx.x];
    }
    __syncthreads();
    int n = blockIdx.x * blockDim.x + threadIdx.x;
    if (n >= N_NODES) return;
    float qa[6], ka[6], va[6], sa[6];
#pragma unroll
    for (int c = 0; c < 6; ++c) { qa[c] = sbq[c]; ka[c] = sbk[c]; va[c] = sbv[c]; sa[c] = sbs[c]; }
    const uint4* hp = reinterpret_cast<const uint4*>(h1 + (size_t)n * 32);
#pragma unroll
    for (int i4 = 0; i4 < 8; ++i4) {
        uint4 hv = hp[i4];
        float2 f01 = __half22float2(*(const __half2*)&hv.x);
        float2 f23 = __half22float2(*(const __half2*)&hv.y);
        float2 f45 = __half22float2(*(const __half2*)&hv.z);
        float2 f67 = __half22float2(*(const __half2*)&hv.w);
        float hvv[8] = {f01.x, f01.y, f23.x, f23.y, f45.x, f45.y, f67.x, f67.y};
#pragma unroll
        for (int uu = 0; uu < 8; ++uu) {
            float hx = hvv[uu];
            int i = i4 * 8 + uu;
#pragma unroll
            for (int c = 0; c < 6; ++c) {
                qa[c] += hx * sWq[i * 6 + c];
                ka[c] += hx * sWk[i * 6 + c];
                va[c] += hx * sWv[i * 6 + c];
                sa[c] += hx * sWs[i * 6 + c];
            }
        }
    }
    const float rsqrt6 = 0.4082482904638631f;
    {
        __half2 h01 = __floats2half2_rn(qa[0] * rsqrt6, qa[1] * rsqrt6);
        __half2 h23 = __floats2half2_rn(qa[2] * rsqrt6, qa[3] * rsqrt6);
        __half2 h45 = __floats2half2_rn(qa[4] * rsqrt6, qa[5] * rsqrt6);
        uint4 w;
        w.x = *(unsigned*)&h01; w.y = *(unsigned*)&h23;
        w.z = *(unsigned*)&h45; w.w = 0u;
        q2h[n] = w;
    }
#pragma unroll
    for (int c = 0; c < 6; ++c) s2[(size_t)n * 6 + c] = sa[c];
    float mk = 0.f, mv = 0.f;
#pragma unroll
    for (int c = 0; c < 6; ++c) {
        mk = fmaxf(mk, fabsf(ka[c]));
        mv = fmaxf(mv, fabsf(va[c]));
    }
    float sk = fmaxf(mk, 1e-8f) * (1.f / 127.f);
    float sv = fmaxf(mv, 1e-8f) * (1.f / 127.f);
    float isk = 1.f / sk, isv = 1.f / sv;
    int qk[6], qv[6];
#pragma unroll
    for (int c = 0; c < 6; ++c) {
        qk[c] = __float2int_rn(ka[c] * isk);
        qv[c] = __float2int_rn(va[c] * isv);
    }
    uint4 w;
    w.x = (qk[0] & 255) | ((qk[1] & 255) << 8) | ((qk[2] & 255) << 16) | ((qk[3] & 255) << 24);
    w.y = (qk[4] & 255) | ((qk[5] & 255) << 8) | ((qv[0] & 255) << 16) | ((qv[1] & 255) << 24);
    w.z = (qv[2] & 255) | ((qv[3] & 255) << 8) | ((qv[4] & 255) << 16) | ((qv[5] & 255) << 24);
    __half2 hs = __floats2half2_rn(sk, sv);
    w.w = *(unsigned*)&hs;
    kv2[n] = w;
}

// ---- G2: two-phase softmax, 8 lanes/node + fused final log_softmax ----
__global__ void g2_layer2(const int* __restrict__ rs, const int* __restrict__ re,
                          const int* __restrict__ csr_src,
                          const uint4* __restrict__ q2h,
                          const uint4* __restrict__ kv2,
                          const float* __restrict__ s2,
                          const int* __restrict__ batch,
                          float* __restrict__ psum, float* __restrict__ pcnt,
                          int* __restrict__ done, float* __restrict__ out) {
    __shared__ float bsum[N_GRAPHS * 6];
    __shared__ float bcnt[N_GRAPHS];
    __shared__ int isLast;
    for (int i = threadIdx.x; i < N_GRAPHS * 6; i += 256) bsum[i] = 0.f;
    for (int i = threadIdx.x; i < N_GRAPHS; i += 256) bcnt[i] = 0.f;
    __syncthreads();

    int node = blockIdx.x * 32 + (threadIdx.x >> 3);
    int lane8 = threadIdx.x & 7;

    uint4 qw = q2h[node];
    float2 q01 = __half22float2(*(const __half2*)&qw.x);
    float2 q23 = __half22float2(*(const __half2*)&qw.y);
    float2 q45 = __half22float2(*(const __half2*)&qw.z);
    float q[6] = {q01.x, q01.y, q23.x, q23.y, q45.x, q45.y};
    int row = rs[node];
    int deg = re[node] - row;

    // phase 1: up to 8 edges/lane in registers (covers deg <= 64)
    float lg[8], svr[8];
    unsigned py[8], pz[8];
#pragma unroll
    for (int i = 0; i < 8; ++i) { lg[i] = NEG_INF; svr[i] = 0.f; py[i] = 0u; pz[i] = 0u; }
    float lmax = NEG_INF;
#pragma unroll
    for (int i = 0; i < 4; ++i) {
        int e = lane8 + i * 8;
        bool v = e < deg;
        int src = v ? csr_src[row + e] : 0;
        uint4 w = kv2[src];
        float svx;
        float l = kvdot(q, w, &svx);
        if (v) {
            lg[i] = l; svr[i] = svx; py[i] = w.y; pz[i] = w.z;
            lmax = fmaxf(lmax, l);
        }
    }
    if (deg > 32) {
#pragma unroll
        for (int i = 4; i < 8; ++i) {
            int e = lane8 + i * 8;
            bool v = e < deg;
            int src = v ? csr_src[row + e] : 0;
            uint4 w = kv2[src];
            float svx;
            float l = kvdot(q, w, &svx);
            if (v) {
                lg[i] = l; svr[i] = svx; py[i] = w.y; pz[i] = w.z;
                lmax = fmaxf(lmax, l);
            }
        }
    }
    // overflow (deg > 64): online fold — essentially never taken, correctness net
    float mo = NEG_INF, dov = 0.f;
    float ao[6] = {0.f, 0.f, 0.f, 0.f, 0.f, 0.f};
    for (int e = lane8 + 64; e < deg; e += 8) {
        int src = csr_src[row + e];
        uint4 w = kv2[src];
        float svx;
        float l = kvdot(q, w, &svx);
        float mn = fmaxf(mo, l);
        float scp = __expf(mo - mn);
        float wx = __expf(l - mn);
        float wsx = wx * svx;
        dov = dov * scp + wx;
        ao[0] = ao[0] * scp + wsx * b2f(w.y, 16);
        ao[1] = ao[1] * scp + wsx * b2f(w.y, 24);
        ao[2] = ao[2] * scp + wsx * b2f(w.z, 0);
        ao[3] = ao[3] * scp + wsx * b2f(w.z, 8);
        ao[4] = ao[4] * scp + wsx * b2f(w.z, 16);
        ao[5] = ao[5] * scp + wsx * b2f(w.z, 24);
        mo = mn;
    }
    lmax = fmaxf(lmax, mo);
    // 3-stage cross-lane max
    lmax = fmaxf(lmax, __shfl_xor(lmax, 1));
    lmax = fmaxf(lmax, __shfl_xor(lmax, 2));
    lmax = fmaxf(lmax, __shfl_xor(lmax, 4));
    if (lmax < -5e29f) lmax = 0.f;   // deg==0 guard

    // phase 2: independent exps, in-lane accumulation (no rescale chain)
    float d = 0.f;
    float acc[6] = {0.f, 0.f, 0.f, 0.f, 0.f, 0.f};
#pragma unroll
    for (int i = 0; i < 8; ++i) {
        float w = __expf(lg[i] - lmax);   // exact 0 for empty slots
        float ws = w * svr[i];
        d += w;
        acc[0] += ws * b2f(py[i], 16);
        acc[1] += ws * b2f(py[i], 24);
        acc[2] += ws * b2f(pz[i], 0);
        acc[3] += ws * b2f(pz[i], 8);
        acc[4] += ws * b2f(pz[i], 16);
        acc[5] += ws * b2f(pz[i], 24);
    }
    // fold overflow state
    float so = __expf(mo - lmax);
    d += dov * so;
#pragma unroll
    for (int c = 0; c < 6; ++c) acc[c] += ao[c] * so;

    // 3-stage butterfly sums
#pragma unroll
    for (int off = 1; off <= 4; off <<= 1) {
        d += __shfl_xor(d, off);
#pragma unroll
        for (int c = 0; c < 6; ++c) acc[c] += __shfl_xor(acc[c], off);
    }

    if (lane8 == 0) {
        float inv = 1.f / (d + 1e-16f);
        int g = batch[node];
#pragma unroll
        for (int c = 0; c < 6; ++c) {
            float val = acc[c] * inv + s2[(size_t)node * 6 + c];
            atomicAdd(&bsum[g * 6 + c], val);
        }
        atomicAdd(&bcnt[g], 1.f);
    }
    __syncthreads();
    for (int i = threadIdx.x; i < N_GRAPHS * 6; i += 256) {
        float v = bsum[i];
        if (v != 0.f) atomAddF(psum + i, v);
    }
    for (int i = threadIdx.x; i < N_GRAPHS; i += 256) {
        float v = bcnt[i];
        if (v != 0.f) atomAddF(pcnt + i, v);
    }

    // ---- fused finalization: last block computes mean + log_softmax ----
    __threadfence();
    __syncthreads();
    if (threadIdx.x == 0) {
        int prev = atomicAdd(done, 1);
        isLast = (prev == (int)gridDim.x - 1) ? 1 : 0;
    }
    __syncthreads();
    if (isLast) {
        __threadfence();
        int g = threadIdx.x;
        if (g < N_GRAPHS) {
            float cnt = fmaxf(pcnt[g], 1.0f);
            float z[6];
            float mx = -1e30f;
#pragma unroll
            for (int c = 0; c < 6; ++c) {
                z[c] = psum[g * 6 + c] / cnt;
                mx = fmaxf(mx, z[c]);
            }
            float se = 0.f;
#pragma unroll
            for (int c = 0; c < 6; ++c) se += __expf(z[c] - mx);
            float lse = mx + logf(se);
#pragma unroll
            for (int c = 0; c < 6; ++c) out[g * 6 + c] = z[c] - lse;
        }
    }
}

extern "C" void kernel_launch(void* const* d_in, const int* in_sizes, int n_in,
                              void* d_out, int out_size, void* d_ws, size_t ws_size,
                              hipStream_t stream) {
    const float* x   = (const float*)d_in[0];
    const int*   ei  = (const int*)d_in[1];
    const int*   bat = (const int*)d_in[2];
    const float* Wq1 = (const float*)d_in[3];  const float* bq1 = (const float*)d_in[4];
    const float* Wk1 = (const float*)d_in[5];  const float* bk1 = (const float*)d_in[6];
    const float* Wv1 = (const float*)d_in[7];  const float* bv1 = (const float*)d_in[8];
    const float* Ws1 = (const float*)d_in[9];  const float* bs1 = (const float*)d_in[10];
    const float* Wq2 = (const float*)d_in[11]; const float* bq2 = (const float*)d_in[12];
    const float* Wk2 = (const float*)d_in[13]; const float* bk2 = (const float*)d_in[14];
    const float* Wv2 = (const float*)d_in[15]; const float* bv2 = (const float*)d_in[16];
    const float* Ws2 = (const float*)d_in[17]; const float* bs2 = (const float*)d_in[18];
    float* out = (float*)d_out;

    char* ws = (char*)d_ws;
    size_t off = 0;
    auto alloc = [&](size_t bytes) -> char* {
        char* p = ws + off;
        off += (bytes + 255) & ~(size_t)255;
        return p;
    };

    // all scratch zero-init handled inside s1 (block 0); no memset needed
    float*    psum    = (float*)   alloc((size_t)N_GRAPHS * 6 * 4);
    float*    pcnt    = (float*)   alloc((size_t)N_GRAPHS * 4);
    int*      done    = (int*)     alloc(256);
    int*      offs    = (int*)     alloc((size_t)NBLK * NB * 4);
    unsigned* pairs   = (unsigned*)alloc((size_t)N_EDGES * 4);
    int*      csr_src = (int*)     alloc((size_t)NB * CAP * 4);
    int*      rsv     = (int*)     alloc((size_t)N_NODES * 4);
    int*      rev     = (int*)     alloc((size_t)N_NODES * 4);
    float4*   xp      = (float4*)  alloc((size_t)N_NODES * 16);
    uint2*    xh      = (uint2*)   alloc((size_t)N_NODES * 8);
    unsigned* h1      = (unsigned*)alloc((size_t)N_NODES * 64 * 2);  // fp16
    uint4*    q2h     = (uint4*)   alloc((size_t)N_NODES * 16);
    float*    s2      = (float*)   alloc((size_t)N_NODES * 6 * 4);
    uint4*    kv2     = (uint4*)   alloc((size_t)N_NODES * 16);

    s1_partition<<<NBLK, 512, 0, stream>>>(ei, x, xp, xh, psum, pcnt, done,
                                           offs, pairs);
    b4_build<<<NB, B4T, 0, stream>>>(pairs, offs, rsv, rev, csr_src);

    g1_layer1<<<N_NODES / 16, 256, 0, stream>>>(xp, xh, Wq1, bq1, Wk1, bk1, Wv1, bv1,
                                                Ws1, bs1, rsv, rev, csr_src,
                                                (uint2*)h1);
    k5_node2<<<(N_NODES + 255) / 256, 256, 0, stream>>>(h1, Wq2, bq2, Wk2, bk2,
                                                        Wv2, bv2, Ws2, bs2,
                                                        q2h, s2, kv2);
    g2_layer2<<<N_NODES / 32, 256, 0, stream>>>(rsv, rev, csr_src, q2h, kv2, s2,
                                                bat, psum, pcnt, done, out);
}

// Round 14
// 135.700 us; speedup vs baseline: 2.3114x; 2.3114x over previous
//
#include <hip/hip_runtime.h>
#include <hip/hip_fp16.h>
#include <math.h>

#define N_NODES 100000
#define N_EDGES 3200000
#define N_GRAPHS 64
#define NEG_INF -1e30f

// bucket sort geometry: bucket = dst >> 9  (512 nodes per bucket)
#define NB 196         // ceil(100000/512)
#define CAP 18432      // per-bucket capacity; mean 16384 + ~16 sigma
#define NBLK 512       // partition blocks
#define CHUNK 6250     // 512 * 6250 = 3.2M exactly

__device__ __forceinline__ void atomAddF(float* p, float v) {
#if defined(__HIP_PLATFORM_AMD__)
    unsafeAtomicAdd(p, v);
#else
    atomicAdd(p, v);
#endif
}

__device__ __forceinline__ float b2f(unsigned w, int sh) {
    return (float)(signed char)(w >> sh);
}

// logit from packed kv row; also extracts v-scale
__device__ __forceinline__ float kvdot(const float* q, uint4 w, float* sv_out) {
    float2 s = __half22float2(*(const __half2*)&w.w);
    *sv_out = s.y;
    return s.x * (q[0] * b2f(w.x, 0) + q[1] * b2f(w.x, 8)
                + q[2] * b2f(w.x, 16) + q[3] * b2f(w.x, 24)
                + q[4] * b2f(w.y, 0) + q[5] * b2f(w.y, 8));
}

// ---- S1: (merged) x-pack + zero-init + in-LDS bucket sort of chunk ----
__global__ __launch_bounds__(512) void s1_partition(const int* __restrict__ ei,
                                                    const float* __restrict__ x,
                                                    float4* __restrict__ xp,
                                                    uint2* __restrict__ xh,
                                                    float* __restrict__ psum,
                                                    float* __restrict__ pcnt,
                                                    int* __restrict__ offs,
                                                    unsigned* __restrict__ pairs) {
    __shared__ unsigned pairbuf[CHUNK];        // 25000 B
    __shared__ unsigned sortbuf[CHUNK];        // 25000 B
    __shared__ unsigned char buckbuf[CHUNK];   // 6250 B
    __shared__ int hist[8][200];               // per-wave, padded
    __shared__ int cur[NB], tmp[NB];
    int tid = threadIdx.x;

    // merged k0: pack this block's slice of nodes (196 per block covers 100352)
    {
        int n = blockIdx.x * 196 + tid;
        if (tid < 196 && n < N_NODES) {
            float x0 = x[3 * n], x1 = x[3 * n + 1], x2 = x[3 * n + 2];
            xp[n] = make_float4(x0, x1, x2, 0.f);
            __half2 h01 = __floats2half2_rn(x0, x1);
            __half2 h2p = __floats2half2_rn(x2, 0.f);
            xh[n] = make_uint2(*(unsigned*)&h01, *(unsigned*)&h2p);
        }
    }
    // merged zero-init (block 0): psum, pcnt
    if (blockIdx.x == 0) {
        for (int i = tid; i < N_GRAPHS * 6; i += 512) psum[i] = 0.f;
        for (int i = tid; i < N_GRAPHS; i += 512) pcnt[i] = 0.f;
    }

    int wp = tid >> 6;                         // 8 waves
    for (int i = tid; i < 8 * 200; i += 512) ((int*)hist)[i] = 0;
    __syncthreads();
    int gbase = blockIdx.x * CHUNK;
    for (int i = tid; i < CHUNK; i += 512) {
        int src = ei[gbase + i];
        unsigned dst = (unsigned)ei[N_EDGES + gbase + i];
        pairbuf[i] = ((unsigned)src << 9) | (dst & 511u);
        unsigned b = dst >> 9;
        buckbuf[i] = (unsigned char)b;
        atomicAdd(&hist[wp][b], 1);
    }
    __syncthreads();
    if (tid < NB) {
        int s = 0;
#pragma unroll
        for (int w = 0; w < 8; ++w) s += hist[w][tid];
        tmp[tid] = s;
        hist[0][tid] = s;                      // stash count for later
    }
    __syncthreads();
    for (int off = 1; off < NB; off <<= 1) {
        int v = 0;
        if (tid < NB && tid >= off) v = tmp[tid - off];
        __syncthreads();
        if (tid < NB) tmp[tid] += v;
        __syncthreads();
    }
    if (tid < NB) {
        int excl = tmp[tid] - hist[0][tid];
        cur[tid] = excl;
        offs[blockIdx.x * NB + tid] = excl;
    }
    __syncthreads();
    for (int i = tid; i < CHUNK; i += 512) {
        int pos = atomicAdd(&cur[buckbuf[i]], 1);
        sortbuf[pos] = pairbuf[i];
    }
    __syncthreads();
    for (int i = tid; i < CHUNK; i += 512)
        pairs[gbase + i] = sortbuf[i];
}

// ---- B4: per-bucket CSR build with full-bucket LDS staging ----
#define B4T 1024
__global__ __launch_bounds__(B4T) void b4_build(const unsigned* __restrict__ pairs,
                                                const int* __restrict__ offs,
                                                int* __restrict__ rs,
                                                int* __restrict__ re,
                                                int* __restrict__ csr_src) {
    __shared__ unsigned eLDS[CAP];             // 73728 B: bucket's edges, dense
    __shared__ int so[NBLK], slen[NBLK], dbase[NBLK];
    __shared__ int cnt2[2][512];
    __shared__ int sc[512], cur[512];
    int b = blockIdx.x;
    int tid = threadIdx.x;

    for (int k = tid; k < NBLK; k += B4T) {
        int s = offs[k * NB + b];
        int e = (b == NB - 1) ? CHUNK : offs[k * NB + b + 1];
        so[k] = s;
        slen[k] = e - s;
    }
    ((int*)cnt2)[tid] = 0;
    __syncthreads();
    // inclusive scan of slen -> dbase (exclusive via -slen)
    if (tid < NBLK) sc[tid] = slen[tid];
    __syncthreads();
    for (int off = 1; off < NBLK; off <<= 1) {
        int v = (tid < NBLK && tid >= off) ? sc[tid - off] : 0;
        __syncthreads();
        if (tid < NBLK) sc[tid] += v;
        __syncthreads();
    }
    if (tid < NBLK) dbase[tid] = sc[tid] - slen[tid];
    __syncthreads();
    int ne = dbase[NBLK - 1] + slen[NBLK - 1];

    // coalesced copy: wave per segment
    int wave = tid >> 6, lane = tid & 63;
    for (int k = wave; k < NBLK; k += (B4T / 64)) {
        int gb = k * CHUNK + so[k];
        int db = dbase[k], ln = slen[k];
        for (int i = lane; i < ln; i += 64)
            eLDS[db + i] = pairs[gb + i];
    }
    __syncthreads();

    // count (from LDS), dual sub-histograms to cut conflicts
    int half = tid >> 9;
    for (int i = tid; i < ne; i += B4T)
        atomicAdd(&cnt2[half][eLDS[i] & 511u], 1);
    __syncthreads();
    int mycnt = 0;
    if (tid < 512) {
        mycnt = cnt2[0][tid] + cnt2[1][tid];
        sc[tid] = mycnt;
    }
    __syncthreads();
    for (int off = 1; off < 512; off <<= 1) {
        int v = (tid < 512 && tid >= off) ? sc[tid - off] : 0;
        __syncthreads();
        if (tid < 512) sc[tid] += v;
        __syncthreads();
    }
    int rbase = b * CAP;
    if (tid < 512) {
        int excl = sc[tid] - mycnt;
        cur[tid] = rbase + excl;
        int node = (b << 9) + tid;
        if (node < N_NODES) {
            rs[node] = rbase + excl;
            re[node] = rbase + sc[tid];
        }
    }
    __syncthreads();
    // scatter (read LDS, write bucket-local global slice)
    for (int i = tid; i < ne; i += B4T) {
        unsigned p = eLDS[i];
        int pos = atomicAdd(&cur[p & 511u], 1);
        csr_src[pos] = (int)(p >> 9);
    }
}

// ---- G1: fused layer-1, rank-3 factorization, fp16 x-gathers, fp16 h1 out ----
__global__ void g1_layer1(const float4* __restrict__ xp,
                          const uint2* __restrict__ xh,
                          const float* __restrict__ Wq, const float* __restrict__ bq,
                          const float* __restrict__ Wk, const float* __restrict__ bk,
                          const float* __restrict__ Wv, const float* __restrict__ bv,
                          const float* __restrict__ Ws, const float* __restrict__ bs,
                          const int* __restrict__ rs, const int* __restrict__ re,
                          const int* __restrict__ csr_src,
                          uint2* __restrict__ h1) {
    __shared__ float sWq[192], sWk[192], sWv[192], sWs[192];
    __shared__ float sbq[64], sbk[64], sbv[64], sbs[64];
    for (int i = threadIdx.x; i < 192; i += 256) {
        sWq[i] = Wq[i]; sWk[i] = Wk[i]; sWv[i] = Wv[i]; sWs[i] = Ws[i];
    }
    for (int i = threadIdx.x; i < 64; i += 256) {
        sbq[i] = bq[i]; sbk[i] = bk[i]; sbv[i] = bv[i]; sbs[i] = bs[i];
    }
    __syncthreads();

    int lane = threadIdx.x & 63;
    int u = lane & 15;
    int slot = u >> 2;
    int j0 = u * 4;
    int n = blockIdx.x * 16 + (threadIdx.x >> 6) * 4 + (lane >> 4);

    float4 xc = xp[n];
    float x0 = xc.x, x1 = xc.y, x2 = xc.z;

    float q[4];
#pragma unroll
    for (int i = 0; i < 4; ++i)
        q[i] = 0.25f * (sbq[j0 + i] + x0 * sWq[j0 + i] + x1 * sWq[64 + j0 + i]
                        + x2 * sWq[128 + j0 + i]);
    float t0 = 0.f, t1 = 0.f, t2 = 0.f, tb = 0.f;
#pragma unroll
    for (int i = 0; i < 4; ++i) {
        float qi = q[i];
        t0 += qi * sWk[j0 + i];
        t1 += qi * sWk[64 + j0 + i];
        t2 += qi * sWk[128 + j0 + i];
        tb += qi * sbk[j0 + i];
    }
#pragma unroll
    for (int off = 1; off <= 2; off <<= 1) {
        t0 += __shfl_xor(t0, off);
        t1 += __shfl_xor(t1, off);
        t2 += __shfl_xor(t2, off);
        tb += __shfl_xor(tb, off);
    }
    // transpose: edge loop wants head = u&3
    int tsrc = (lane & 48) | ((lane & 3) << 2) | ((lane >> 2) & 3);
    t0 = __shfl(t0, tsrc, 64);
    t1 = __shfl(t1, tsrc, 64);
    t2 = __shfl(t2, tsrc, 64);
    tb = __shfl(tb, tsrc, 64);

    int row = rs[n];
    int deg = re[n] - row;

    float mA = NEG_INF, dA = 0.f, s0A = 0.f, s1A = 0.f, s2A = 0.f;
    float mB = NEG_INF, dB = 0.f, s0B = 0.f, s1B = 0.f, s2B = 0.f;
    for (int base = 0; base < deg; base += 8) {
        int eA = base + slot, eB = base + 4 + slot;
        bool vA = eA < deg, vB = eB < deg;
        int srcA = vA ? csr_src[row + eA] : 0;
        int srcB = vB ? csr_src[row + eB] : 0;
        uint2 wA = xh[srcA];
        uint2 wB = xh[srcB];
        float2 a01 = __half22float2(*(const __half2*)&wA.x);
        float a2 = __half22float2(*(const __half2*)&wA.y).x;
        float2 b01 = __half22float2(*(const __half2*)&wB.x);
        float b2 = __half22float2(*(const __half2*)&wB.y).x;
        float lA = vA ? (tb + a01.x * t0 + a01.y * t1 + a2 * t2) : NEG_INF;
        float lB = vB ? (tb + b01.x * t0 + b01.y * t1 + b2 * t2) : NEG_INF;
        float mnA = fmaxf(mA, lA);
        float scA = __expf(mA - mnA);
        float aA = vA ? __expf(lA - mnA) : 0.f;
        dA = dA * scA + aA;
        s0A = s0A * scA + aA * a01.x;
        s1A = s1A * scA + aA * a01.y;
        s2A = s2A * scA + aA * a2;
        mA = mnA;
        float mnB = fmaxf(mB, lB);
        float scB = __expf(mB - mnB);
        float aB = vB ? __expf(lB - mnB) : 0.f;
        dB = dB * scB + aB;
        s0B = s0B * scB + aB * b01.x;
        s1B = s1B * scB + aB * b01.y;
        s2B = s2B * scB + aB * b2;
        mB = mnB;
    }
    // merge B into A (in-lane)
    float m = fmaxf(mA, mB);
    float fA = __expf(mA - m), fB = __expf(mB - m);
    float d = dA * fA + dB * fB;
    float s0 = s0A * fA + s0B * fB;
    float s1 = s1A * fA + s1B * fB;
    float s2 = s2A * fA + s2B * fB;

    // cross-slot merge: global max, single rescale, butterfly sums
    float gm = m;
    gm = fmaxf(gm, __shfl_xor(gm, 4));
    gm = fmaxf(gm, __shfl_xor(gm, 8));
    float f = __expf(m - gm);
    d *= f; s0 *= f; s1 *= f; s2 *= f;
#pragma unroll
    for (int off = 4; off <= 8; off <<= 1) {
        d += __shfl_xor(d, off);
        s0 += __shfl_xor(s0, off);
        s1 += __shfl_xor(s1, off);
        s2 += __shfl_xor(s2, off);
    }

    // epilogue: lane u needs head u>>2's state
    int esrc = (lane & 48) | ((lane >> 2) & 3);
    float dH = __shfl(d, esrc, 64);
    float s0H = __shfl(s0, esrc, 64);
    float s1H = __shfl(s1, esrc, 64);
    float s2H = __shfl(s2, esrc, 64);
    float inv = 1.f / (dH + 1e-16f);
    float fr = dH * inv, r0 = s0H * inv, r1 = s1H * inv, r2 = s2H * inv;

    float o[4];
#pragma unroll
    for (int i = 0; i < 4; ++i) {
        int j = j0 + i;
        float val = fr * sbv[j] + r0 * sWv[j] + r1 * sWv[64 + j] + r2 * sWv[128 + j]
                  + sbs[j] + x0 * sWs[j] + x1 * sWs[64 + j] + x2 * sWs[128 + j];
        o[i] = fmaxf(val, 0.f);
    }
    __half2 p01 = __floats2half2_rn(o[0], o[1]);
    __half2 p23 = __floats2half2_rn(o[2], o[3]);
    h1[(size_t)n * 16 + u] = make_uint2(*(unsigned*)&p01, *(unsigned*)&p23);
}

// ---- K5: reads fp16 h1; q2h fp16-packed (pre-scaled) + s2 fp32; kv2 int8 ----
__global__ void k5_node2(const unsigned* __restrict__ h1,
                         const float* __restrict__ Wq, const float* __restrict__ bq,
                         const float* __restrict__ Wk, const float* __restrict__ bk,
                         const float* __restrict__ Wv, const float* __restrict__ bv,
                         const float* __restrict__ Ws, const float* __restrict__ bs,
                         uint4* __restrict__ q2h, float* __restrict__ s2,
                         uint4* __restrict__ kv2) {
    __shared__ float sWq[384], sWk[384], sWv[384], sWs[384];
    __shared__ float sbq[6], sbk[6], sbv[6], sbs[6];
    for (int i = threadIdx.x; i < 384; i += blockDim.x) {
        sWq[i] = Wq[i]; sWk[i] = Wk[i]; sWv[i] = Wv[i]; sWs[i] = Ws[i];
    }
    if (threadIdx.x < 6) {
        sbq[threadIdx.x] = bq[threadIdx.x];
        sbk[threadIdx.x] = bk[threadIdx.x];
        sbv[threadIdx.x] = bv[threadIdx.x];
        sbs[threadIdx.x] = bs[threadIdx.x];
    }
    __syncthreads();
    int n = blockIdx.x * blockDim.x + threadIdx.x;
    if (n >= N_NODES) return;
    float qa[6], ka[6], va[6], sa[6];
#pragma unroll
    for (int c = 0; c < 6; ++c) { qa[c] = sbq[c]; ka[c] = sbk[c]; va[c] = sbv[c]; sa[c] = sbs[c]; }
    const uint4* hp = reinterpret_cast<const uint4*>(h1 + (size_t)n * 32);
#pragma unroll
    for (int i4 = 0; i4 < 8; ++i4) {
        uint4 hv = hp[i4];
        float2 f01 = __half22float2(*(const __half2*)&hv.x);
        float2 f23 = __half22float2(*(const __half2*)&hv.y);
        float2 f45 = __half22float2(*(const __half2*)&hv.z);
        float2 f67 = __half22float2(*(const __half2*)&hv.w);
        float hvv[8] = {f01.x, f01.y, f23.x, f23.y, f45.x, f45.y, f67.x, f67.y};
#pragma unroll
        for (int uu = 0; uu < 8; ++uu) {
            float hx = hvv[uu];
            int i = i4 * 8 + uu;
#pragma unroll
            for (int c = 0; c < 6; ++c) {
                qa[c] += hx * sWq[i * 6 + c];
                ka[c] += hx * sWk[i * 6 + c];
                va[c] += hx * sWv[i * 6 + c];
                sa[c] += hx * sWs[i * 6 + c];
            }
        }
    }
    const float rsqrt6 = 0.4082482904638631f;
    {
        __half2 h01 = __floats2half2_rn(qa[0] * rsqrt6, qa[1] * rsqrt6);
        __half2 h23 = __floats2half2_rn(qa[2] * rsqrt6, qa[3] * rsqrt6);
        __half2 h45 = __floats2half2_rn(qa[4] * rsqrt6, qa[5] * rsqrt6);
        uint4 w;
        w.x = *(unsigned*)&h01; w.y = *(unsigned*)&h23;
        w.z = *(unsigned*)&h45; w.w = 0u;
        q2h[n] = w;
    }
#pragma unroll
    for (int c = 0; c < 6; ++c) s2[(size_t)n * 6 + c] = sa[c];
    float mk = 0.f, mv = 0.f;
#pragma unroll
    for (int c = 0; c < 6; ++c) {
        mk = fmaxf(mk, fabsf(ka[c]));
        mv = fmaxf(mv, fabsf(va[c]));
    }
    float sk = fmaxf(mk, 1e-8f) * (1.f / 127.f);
    float sv = fmaxf(mv, 1e-8f) * (1.f / 127.f);
    float isk = 1.f / sk, isv = 1.f / sv;
    int qk[6], qv[6];
#pragma unroll
    for (int c = 0; c < 6; ++c) {
        qk[c] = __float2int_rn(ka[c] * isk);
        qv[c] = __float2int_rn(va[c] * isv);
    }
    uint4 w;
    w.x = (qk[0] & 255) | ((qk[1] & 255) << 8) | ((qk[2] & 255) << 16) | ((qk[3] & 255) << 24);
    w.y = (qk[4] & 255) | ((qk[5] & 255) << 8) | ((qv[0] & 255) << 16) | ((qv[1] & 255) << 24);
    w.z = (qv[2] & 255) | ((qv[3] & 255) << 8) | ((qv[4] & 255) << 16) | ((qv[5] & 255) << 24);
    __half2 hs = __floats2half2_rn(sk, sv);
    w.w = *(unsigned*)&hs;
    kv2[n] = w;
}

// ---- G2: two-phase softmax, 8 lanes/node, register-resident edges ----
__global__ void g2_layer2(const int* __restrict__ rs, const int* __restrict__ re,
                          const int* __restrict__ csr_src,
                          const uint4* __restrict__ q2h,
                          const uint4* __restrict__ kv2,
                          const float* __restrict__ s2,
                          const int* __restrict__ batch,
                          float* __restrict__ psum, float* __restrict__ pcnt) {
    __shared__ float bsum[N_GRAPHS * 6];
    __shared__ float bcnt[N_GRAPHS];
    for (int i = threadIdx.x; i < N_GRAPHS * 6; i += 256) bsum[i] = 0.f;
    for (int i = threadIdx.x; i < N_GRAPHS; i += 256) bcnt[i] = 0.f;
    __syncthreads();

    int node = blockIdx.x * 32 + (threadIdx.x >> 3);
    int lane8 = threadIdx.x & 7;

    uint4 qw = q2h[node];
    float2 q01 = __half22float2(*(const __half2*)&qw.x);
    float2 q23 = __half22float2(*(const __half2*)&qw.y);
    float2 q45 = __half22float2(*(const __half2*)&qw.z);
    float q[6] = {q01.x, q01.y, q23.x, q23.y, q45.x, q45.y};
    int row = rs[node];
    int deg = re[node] - row;

    // phase 1: up to 8 edges/lane in registers (covers deg <= 64)
    float lg[8], svr[8];
    unsigned py[8], pz[8];
#pragma unroll
    for (int i = 0; i < 8; ++i) { lg[i] = NEG_INF; svr[i] = 0.f; py[i] = 0u; pz[i] = 0u; }
    float lmax = NEG_INF;
#pragma unroll
    for (int i = 0; i < 4; ++i) {
        int e = lane8 + i * 8;
        bool v = e < deg;
        int src = v ? csr_src[row + e] : 0;
        uint4 w = kv2[src];
        float svx;
        float l = kvdot(q, w, &svx);
        if (v) {
            lg[i] = l; svr[i] = svx; py[i] = w.y; pz[i] = w.z;
            lmax = fmaxf(lmax, l);
        }
    }
    if (deg > 32) {
#pragma unroll
        for (int i = 4; i < 8; ++i) {
            int e = lane8 + i * 8;
            bool v = e < deg;
            int src = v ? csr_src[row + e] : 0;
            uint4 w = kv2[src];
            float svx;
            float l = kvdot(q, w, &svx);
            if (v) {
                lg[i] = l; svr[i] = svx; py[i] = w.y; pz[i] = w.z;
                lmax = fmaxf(lmax, l);
            }
        }
    }
    // overflow (deg > 64): online fold — essentially never taken, correctness net
    float mo = NEG_INF, dov = 0.f;
    float ao[6] = {0.f, 0.f, 0.f, 0.f, 0.f, 0.f};
    for (int e = lane8 + 64; e < deg; e += 8) {
        int src = csr_src[row + e];
        uint4 w = kv2[src];
        float svx;
        float l = kvdot(q, w, &svx);
        float mn = fmaxf(mo, l);
        float scp = __expf(mo - mn);
        float wx = __expf(l - mn);
        float wsx = wx * svx;
        dov = dov * scp + wx;
        ao[0] = ao[0] * scp + wsx * b2f(w.y, 16);
        ao[1] = ao[1] * scp + wsx * b2f(w.y, 24);
        ao[2] = ao[2] * scp + wsx * b2f(w.z, 0);
        ao[3] = ao[3] * scp + wsx * b2f(w.z, 8);
        ao[4] = ao[4] * scp + wsx * b2f(w.z, 16);
        ao[5] = ao[5] * scp + wsx * b2f(w.z, 24);
        mo = mn;
    }
    lmax = fmaxf(lmax, mo);
    // 3-stage cross-lane max
    lmax = fmaxf(lmax, __shfl_xor(lmax, 1));
    lmax = fmaxf(lmax, __shfl_xor(lmax, 2));
    lmax = fmaxf(lmax, __shfl_xor(lmax, 4));
    if (lmax < -5e29f) lmax = 0.f;   // deg==0 guard

    // phase 2: independent exps, in-lane accumulation (no rescale chain)
    float d = 0.f;
    float acc[6] = {0.f, 0.f, 0.f, 0.f, 0.f, 0.f};
#pragma unroll
    for (int i = 0; i < 8; ++i) {
        float w = __expf(lg[i] - lmax);   // exact 0 for empty slots
        float ws = w * svr[i];
        d += w;
        acc[0] += ws * b2f(py[i], 16);
        acc[1] += ws * b2f(py[i], 24);
        acc[2] += ws * b2f(pz[i], 0);
        acc[3] += ws * b2f(pz[i], 8);
        acc[4] += ws * b2f(pz[i], 16);
        acc[5] += ws * b2f(pz[i], 24);
    }
    // fold overflow state
    float so = __expf(mo - lmax);
    d += dov * so;
#pragma unroll
    for (int c = 0; c < 6; ++c) acc[c] += ao[c] * so;

    // 3-stage butterfly sums
#pragma unroll
    for (int off = 1; off <= 4; off <<= 1) {
        d += __shfl_xor(d, off);
#pragma unroll
        for (int c = 0; c < 6; ++c) acc[c] += __shfl_xor(acc[c], off);
    }

    if (lane8 == 0) {
        float inv = 1.f / (d + 1e-16f);
        int g = batch[node];
#pragma unroll
        for (int c = 0; c < 6; ++c) {
            float val = acc[c] * inv + s2[(size_t)node * 6 + c];
            atomicAdd(&bsum[g * 6 + c], val);
        }
        atomicAdd(&bcnt[g], 1.f);
    }
    __syncthreads();
    for (int i = threadIdx.x; i < N_GRAPHS * 6; i += 256) {
        float v = bsum[i];
        if (v != 0.f) atomAddF(psum + i, v);
    }
    for (int i = threadIdx.x; i < N_GRAPHS; i += 256) {
        float v = bcnt[i];
        if (v != 0.f) atomAddF(pcnt + i, v);
    }
}

// ---- K9: pooled mean + log_softmax ----
__global__ void k9_final(const float* __restrict__ psum, const float* __restrict__ pcnt,
                         float* __restrict__ out) {
    int g = threadIdx.x;
    if (g >= N_GRAPHS) return;
    float cnt = fmaxf(pcnt[g], 1.0f);
    float z[6];
    float mx = -1e30f;
#pragma unroll
    for (int c = 0; c < 6; ++c) {
        z[c] = psum[g * 6 + c] / cnt;
        mx = fmaxf(mx, z[c]);
    }
    float se = 0.f;
#pragma unroll
    for (int c = 0; c < 6; ++c) se += __expf(z[c] - mx);
    float lse = mx + logf(se);
#pragma unroll
    for (int c = 0; c < 6; ++c) out[g * 6 + c] = z[c] - lse;
}

extern "C" void kernel_launch(void* const* d_in, const int* in_sizes, int n_in,
                              void* d_out, int out_size, void* d_ws, size_t ws_size,
                              hipStream_t stream) {
    const float* x   = (const float*)d_in[0];
    const int*   ei  = (const int*)d_in[1];
    const int*   bat = (const int*)d_in[2];
    const float* Wq1 = (const float*)d_in[3];  const float* bq1 = (const float*)d_in[4];
    const float* Wk1 = (const float*)d_in[5];  const float* bk1 = (const float*)d_in[6];
    const float* Wv1 = (const float*)d_in[7];  const float* bv1 = (const float*)d_in[8];
    const float* Ws1 = (const float*)d_in[9];  const float* bs1 = (const float*)d_in[10];
    const float* Wq2 = (const float*)d_in[11]; const float* bq2 = (const float*)d_in[12];
    const float* Wk2 = (const float*)d_in[13]; const float* bk2 = (const float*)d_in[14];
    const float* Wv2 = (const float*)d_in[15]; const float* bv2 = (const float*)d_in[16];
    const float* Ws2 = (const float*)d_in[17]; const float* bs2 = (const float*)d_in[18];
    float* out = (float*)d_out;

    char* ws = (char*)d_ws;
    size_t off = 0;
    auto alloc = [&](size_t bytes) -> char* {
        char* p = ws + off;
        off += (bytes + 255) & ~(size_t)255;
        return p;
    };

    // all scratch zero-init handled inside s1 (block 0); no memset needed
    float*    psum    = (float*)   alloc((size_t)N_GRAPHS * 6 * 4);
    float*    pcnt    = (float*)   alloc((size_t)N_GRAPHS * 4);
    int*      offs    = (int*)     alloc((size_t)NBLK * NB * 4);
    unsigned* pairs   = (unsigned*)alloc((size_t)N_EDGES * 4);
    int*      csr_src = (int*)     alloc((size_t)NB * CAP * 4);
    int*      rsv     = (int*)     alloc((size_t)N_NODES * 4);
    int*      rev     = (int*)     alloc((size_t)N_NODES * 4);
    float4*   xp      = (float4*)  alloc((size_t)N_NODES * 16);
    uint2*    xh      = (uint2*)   alloc((size_t)N_NODES * 8);
    unsigned* h1      = (unsigned*)alloc((size_t)N_NODES * 64 * 2);  // fp16
    uint4*    q2h     = (uint4*)   alloc((size_t)N_NODES * 16);
    float*    s2      = (float*)   alloc((size_t)N_NODES * 6 * 4);
    uint4*    kv2     = (uint4*)   alloc((size_t)N_NODES * 16);

    s1_partition<<<NBLK, 512, 0, stream>>>(ei, x, xp, xh, psum, pcnt, offs, pairs);
    b4_build<<<NB, B4T, 0, stream>>>(pairs, offs, rsv, rev, csr_src);

    g1_layer1<<<N_NODES / 16, 256, 0, stream>>>(xp, xh, Wq1, bq1, Wk1, bk1, Wv1, bv1,
                                                Ws1, bs1, rsv, rev, csr_src,
                                                (uint2*)h1);
    k5_node2<<<(N_NODES + 255) / 256, 256, 0, stream>>>(h1, Wq2, bq2, Wk2, bk2,
                                                        Wv2, bv2, Ws2, bs2,
                                                        q2h, s2, kv2);
    g2_layer2<<<N_NODES / 32, 256, 0, stream>>>(rsv, rev, csr_src, q2h, kv2, s2,
                                                bat, psum, pcnt);
    k9_final<<<1, 64, 0, stream>>>(psum, pcnt, out);
}